// Round 20
// baseline (330.271 us; speedup 1.0000x reference)
//
#include <hip/hip_runtime.h>
#include <hip/hip_bf16.h>

// Problem constants (B=4, C=64, N=8192, K=16, D=64)
#define NPTS 8192
#define NQ   32768      // B*N
#define KNN  16
#define SCAP 112        // survivor cap per query (expected ~25-50)

// ws layout (bytes)
#define OFF_XT   0                      // B*N*C f32 = 8 MB  (x transposed to (B,N,C))
#define OFF_FBIG (8*1024*1024)          // 17*64*64 f32 = 278528 B (F with appended -sum(F))
#define OFF_SUMS (OFF_FBIG + 278528)    // 128 f32 (sum, sumsq per channel)
#define OFF_IDX  (OFF_SUMS + 512)       // B*N*16 int32 = 2 MB
#define OFF_PRE  (OFF_IDX + 2*1024*1024)// B*N*64 f32 = 8 MB (pre-BN output, (B*N, D))
// sq array (B*N f32 = 128 KB) ALIASES the start of PRE: k_prep writes it,
// k_knn consumes it, then k_conv overwrites PRE — stream-ordered, safe.
#define OFF_SQ   OFF_PRE

// Reference fp32 key — numpy execution model (verified R6, absmax 0.0156):
//   sq[m]   = (x*x + y*y) + z*z                  -- non-fused (np.sum(pos*pos))
//   inner   = fma(z,z', fma(y,y', rnd(x*x')))    -- einsum AVX2 axpy FMA chain
//   negd    = ((2*inner) - sq_n) - sq_m          -- elementwise, left-to-right
__device__ __forceinline__ float sq3(float x, float y, float z) {
    #pragma clang fp contract(off)
    float xx = x * x;
    float yy = y * y;
    float zz = z * z;
    return (xx + yy) + zz;
}
__device__ __forceinline__ float negd2(float qx, float qy, float qz, float sqn,
                                       float mx, float my, float mz, float sqm) {
    #pragma clang fp contract(off)
    float p0 = qx * mx;
    float inn = __builtin_fmaf(qz, mz, __builtin_fmaf(qy, my, p0));
    float t = 2.0f * inn;
    float u = t - sqn;
    return u - sqm;
}
// Filter margin: cheap fused key c~ = 2<q,m> - sqm differs from (exact key +
// sqn) by <= ~1e-4. 2e-3 is 20x conservative; two eps-steps cover tau-side
// and member-side error -> survivor set provably supersets the true top-16.
#define KEY_EPS2 2.0e-3f

// ---------------- K0: merged prep (transpose x | Fbig | zero sums | sq) ------
__global__ __launch_bounds__(256) void k_prep(const float* __restrict__ x,
                                              const float* __restrict__ F,
                                              const float* __restrict__ pos,
                                              float* __restrict__ xT,
                                              float* __restrict__ Fb,
                                              float* __restrict__ sums,
                                              float* __restrict__ sqa) {
    int bid = blockIdx.x;
    if (bid < 512) {
        __shared__ float tile[64][65];
        int lane = threadIdx.x & 63, wid = threadIdx.x >> 6;
        int b = bid >> 7, nt = bid & 127;
        int n0 = nt * 64;
        for (int rr = 0; rr < 16; ++rr) {
            int c = wid * 16 + rr;
            tile[c][lane] = x[((size_t)b * 64 + c) * NPTS + n0 + lane];
        }
        __syncthreads();
        for (int rr = 0; rr < 16; ++rr) {
            int r = wid * 16 + rr;
            xT[((size_t)(b * NPTS + n0 + r)) * 64 + lane] = tile[lane][r];
        }
    } else if (bid < 528) {
        int j = bid - 512;
        for (int e = threadIdx.x; e < 4096; e += 256)
            Fb[j * 4096 + e] = F[j * 4096 + e];
    } else if (bid == 528) {
        for (int e = threadIdx.x; e < 4096; e += 256) {
            float s = 0.f;
            for (int k = 0; k < 16; ++k) s += F[k * 4096 + e];
            Fb[16 * 4096 + e] = -s;
        }
    } else if (bid == 529) {
        if (threadIdx.x < 128) sums[threadIdx.x] = 0.f;
    } else {
        int g = (bid - 530) * 256 + threadIdx.x;   // 0..NQ-1
        int b = g >> 13, n = g & (NPTS - 1);
        const float* pb = pos + (size_t)b * 3 * NPTS;
        sqa[g] = sq3(pb[n], pb[NPTS + n], pb[2 * NPTS + n]);
    }
}

// ---------------- K1: kNN — candidate-split waves, relaxed VGPR budget -------
// R19 lesson: (256,8)'s hard 64-VGPR cap made the allocator SPILL (VGPR=32,
// +8MB scratch writes) — occupancy doubled but spill traffic ate it. Fix:
// (256,4) budget; the body's live set (~56 regs: tq[24] + loop state) should
// land <=64 naturally, and HW grants 8 waves/SIMD whenever vgpr<=64 — the
// 2048-block grid (8 blocks/CU) supplies them without any bound.
__global__ __launch_bounds__(256, 4) void k_knn(const float* __restrict__ pos,
                                                const float* __restrict__ sqa,
                                                int* __restrict__ idxo) {
    __shared__ int            cnt[16];
    __shared__ unsigned short sidx[16][SCAP];
    __shared__ float          skey[16][SCAP];
    __shared__ int            outI[16][16];
    __shared__ float          taus[16][2];
    int t = threadIdx.x, lane = t & 63, wid = t >> 6;
    int grp = wid >> 1, half = wid & 1;
    int qblk = blockIdx.x * 16;               // 16 queries per block, same batch
    int b = qblk >> 13;
    const float* px = pos + (size_t)b * 3 * NPTS;
    const float* py = px + NPTS;
    const float* pz = py + NPTS;
    const float* sb = sqa + (size_t)b * NPTS;
    int nbase = qblk & (NPTS - 1);
    int n0 = nbase + grp * 8;                 // this wave pair's 8 queries

    // only the doubled query coords stay hot (24 regs); exact-key inputs are
    // reloaded in phase A (L2-hot) to keep the live set small.
    float tqx[8], tqy[8], tqz[8];
    #pragma unroll
    for (int i = 0; i < 8; ++i) {
        tqx[i] = 2.0f * px[n0 + i];
        tqy[i] = 2.0f * py[n0 + i];
        tqz[i] = 2.0f * pz[n0 + i];
    }
    if (t < 16) cnt[t] = 0;
    outI[t >> 4][t & 15] = nbase + (t >> 4);  // fallback: self (in-range)

    // pass 1: per-lane max of cheap key over OWN HALF (3 FMA + max3 tree)
    float lm[8];
    #pragma unroll
    for (int i = 0; i < 8; ++i) lm[i] = -3.4e38f;
    for (int it = 0; it < 16; ++it) {
        int m = half * 4096 + it * 256 + lane * 4;
        float4 X = *(const float4*)(px + m);
        float4 Y = *(const float4*)(py + m);
        float4 Z = *(const float4*)(pz + m);
        float4 S = *(const float4*)(sb + m);
        #pragma unroll
        for (int i = 0; i < 8; ++i) {
            float a0 = __builtin_fmaf(tqx[i], X.x, __builtin_fmaf(tqy[i], Y.x, __builtin_fmaf(tqz[i], Z.x, -S.x)));
            float a1 = __builtin_fmaf(tqx[i], X.y, __builtin_fmaf(tqy[i], Y.y, __builtin_fmaf(tqz[i], Z.y, -S.y)));
            float a2 = __builtin_fmaf(tqx[i], X.z, __builtin_fmaf(tqy[i], Y.z, __builtin_fmaf(tqz[i], Z.z, -S.z)));
            float a3 = __builtin_fmaf(tqx[i], X.w, __builtin_fmaf(tqy[i], Y.w, __builtin_fmaf(tqz[i], Z.w, -S.w)));
            float m012 = fmaxf(fmaxf(a0, a1), a2);
            lm[i] = fmaxf(fmaxf(m012, a3), lm[i]);
        }
    }

    // per-half tau[i] = 16th largest of 64 lane maxima; publish to LDS
    #pragma unroll
    for (int i = 0; i < 8; ++i) {
        float val = lm[i], tv = 0.f;
        for (int r = 0; r < 16; ++r) {
            float mm = val;
            mm = fmaxf(mm, __shfl_xor(mm, 1, 64));
            mm = fmaxf(mm, __shfl_xor(mm, 2, 64));
            mm = fmaxf(mm, __shfl_xor(mm, 4, 64));
            mm = fmaxf(mm, __shfl_xor(mm, 8, 64));
            mm = fmaxf(mm, __shfl_xor(mm, 16, 64));
            mm = fmaxf(mm, __shfl_xor(mm, 32, 64));
            tv = mm;
            if (val == mm) val = -3.4e38f;   // ties pop together: tau shrinks -> superset
        }
        if (lane == 0) taus[grp * 8 + i][half] = tv;
    }
    __syncthreads();

    // merged thresholds: max(tau0,tau1) has >=16 distinct cands above it
    float thr[8];
    #pragma unroll
    for (int i = 0; i < 8; ++i)
        thr[i] = fmaxf(taus[grp * 8 + i][0], taus[grp * 8 + i][1]) - KEY_EPS2;

    // pass 2: collect survivors from OWN HALF (lists shared by wave pair)
    for (int it = 0; it < 16; ++it) {
        int m = half * 4096 + it * 256 + lane * 4;
        float4 X = *(const float4*)(px + m);
        float4 Y = *(const float4*)(py + m);
        float4 Z = *(const float4*)(pz + m);
        float4 S = *(const float4*)(sb + m);
        #pragma unroll
        for (int i = 0; i < 8; ++i) {
            int lq = grp * 8 + i;
            float a0 = __builtin_fmaf(tqx[i], X.x, __builtin_fmaf(tqy[i], Y.x, __builtin_fmaf(tqz[i], Z.x, -S.x)));
            float a1 = __builtin_fmaf(tqx[i], X.y, __builtin_fmaf(tqy[i], Y.y, __builtin_fmaf(tqz[i], Z.y, -S.y)));
            float a2 = __builtin_fmaf(tqx[i], X.z, __builtin_fmaf(tqy[i], Y.z, __builtin_fmaf(tqz[i], Z.z, -S.z)));
            float a3 = __builtin_fmaf(tqx[i], X.w, __builtin_fmaf(tqy[i], Y.w, __builtin_fmaf(tqz[i], Z.w, -S.w)));
            if (a0 >= thr[i]) { int s_ = atomicAdd(&cnt[lq],1); if (s_<SCAP) sidx[lq][s_] = (unsigned short)m; }
            if (a1 >= thr[i]) { int s_ = atomicAdd(&cnt[lq],1); if (s_<SCAP) sidx[lq][s_] = (unsigned short)(m+1); }
            if (a2 >= thr[i]) { int s_ = atomicAdd(&cnt[lq],1); if (s_<SCAP) sidx[lq][s_] = (unsigned short)(m+2); }
            if (a3 >= thr[i]) { int s_ = atomicAdd(&cnt[lq],1); if (s_<SCAP) sidx[lq][s_] = (unsigned short)(m+3); }
        }
    }
    __syncthreads();

    // phase A: exact reference key per survivor; wave handles 4 queries.
    #pragma unroll 1
    for (int i = 0; i < 4; ++i) {
        int lq = wid * 4 + i;
        int qn = nbase + lq;
        float qx = px[qn], qy = py[qn], qz = pz[qn], sqn = sb[qn];
        int S = cnt[lq]; if (S > SCAP) S = SCAP;
        for (int p = lane; p < S; p += 64) {
            int m = sidx[lq][p];
            skey[lq][p] = negd2(qx, qy, qz, sqn, px[m], py[m], pz[m], sb[m]);
        }
    }
    __syncthreads();

    // phase B: exact rerank; ties -> lower index (lax.top_k semantics)
    #pragma unroll 1
    for (int i = 0; i < 4; ++i) {
        int lq = wid * 4 + i;
        int S = cnt[lq]; if (S > SCAP) S = SCAP;
        for (int p = lane; p < S; p += 64) {
            int m = sidx[lq][p];
            float km = skey[lq][p];
            int rank = 0;
            for (int j = 0; j < S; ++j) {
                float kj = skey[lq][j];
                int ij = sidx[lq][j];
                if (kj > km || (kj == km && ij < m)) rank++;
            }
            if (rank < KNN) outI[lq][rank] = m;
        }
    }
    __syncthreads();
    // write out 16 queries x 16 ranks (one value per thread)
    idxo[(size_t)(qblk + (t >> 4)) * KNN + (t & 15)] = outI[t >> 4][t & 15];
}

// ---------------- K2: gather + GEMM + fused BN-stats (R13 proven) ------------
// 64q x 64d tile, 256 threads, 4x4 micro, 2 blocks/CU. LDS-pipe-bound.
// R10/R14 bigger-micro variants both cliffed on occupancy; keep this shape.
#define CPAD 68
__global__ __launch_bounds__(256) void k_conv(const float* __restrict__ xT,
                                              const float* __restrict__ Fb,
                                              const int* __restrict__ idx,
                                              float* __restrict__ outp,
                                              float* __restrict__ sums) {
    __shared__ float At[64][CPAD];
    __shared__ float Bt[64 * 64];
    int t = threadIdx.x;
    int q0 = blockIdx.x * 64;                 // tile base (same batch: 8192%64==0)
    int bbase = q0 & ~(NPTS - 1);             // batch row offset in xT
    int qi0 = (t >> 4) * 4;                   // query sub-block 0..60
    int dj0 = (t & 15) * 4;                   // d sub-block 0..60
    int r = t & 63;                           // gather row
    int s = t >> 6;                           // 16-float segment

    float acc[4][4];
    #pragma unroll
    for (int a = 0; a < 4; ++a)
        #pragma unroll
        for (int bb = 0; bb < 4; ++bb) acc[a][bb] = 0.f;

    for (int j = 0; j < 17; ++j) {
        // ---- stage A: gather 64 neighbor rows, store transposed ----
        {
            int qg = q0 + r;
            int nbr = (j < 16) ? (idx[(size_t)qg * KNN + j] & (NPTS - 1))
                               : (qg & (NPTS - 1));
            const float* src = xT + ((size_t)(bbase + nbr) * 64 + s * 16);
            float4 v0 = *(const float4*)(src);
            float4 v1 = *(const float4*)(src + 4);
            float4 v2 = *(const float4*)(src + 8);
            float4 v3 = *(const float4*)(src + 12);
            int c0 = s * 16;
            At[c0+ 0][r] = v0.x; At[c0+ 1][r] = v0.y; At[c0+ 2][r] = v0.z; At[c0+ 3][r] = v0.w;
            At[c0+ 4][r] = v1.x; At[c0+ 5][r] = v1.y; At[c0+ 6][r] = v1.z; At[c0+ 7][r] = v1.w;
            At[c0+ 8][r] = v2.x; At[c0+ 9][r] = v2.y; At[c0+10][r] = v2.z; At[c0+11][r] = v2.w;
            At[c0+12][r] = v3.x; At[c0+13][r] = v3.y; At[c0+14][r] = v3.z; At[c0+15][r] = v3.w;
        }
        // ---- stage B: copy F[j] (4096 floats) ----
        {
            const float* fj = Fb + j * 4096;
            #pragma unroll
            for (int u = 0; u < 4; ++u) {
                int e = u * 1024 + t * 4;
                *(float4*)&Bt[e] = *(const float4*)(fj + e);
            }
        }
        __syncthreads();
        // ---- compute: 64 k-steps ----
        #pragma unroll 8
        for (int k = 0; k < 64; ++k) {
            float4 av = *(const float4*)&At[k][qi0];
            float4 bv = *(const float4*)&Bt[k * 64 + dj0];
            acc[0][0] = fmaf(av.x, bv.x, acc[0][0]);
            acc[0][1] = fmaf(av.x, bv.y, acc[0][1]);
            acc[0][2] = fmaf(av.x, bv.z, acc[0][2]);
            acc[0][3] = fmaf(av.x, bv.w, acc[0][3]);
            acc[1][0] = fmaf(av.y, bv.x, acc[1][0]);
            acc[1][1] = fmaf(av.y, bv.y, acc[1][1]);
            acc[1][2] = fmaf(av.y, bv.z, acc[1][2]);
            acc[1][3] = fmaf(av.y, bv.w, acc[1][3]);
            acc[2][0] = fmaf(av.z, bv.x, acc[2][0]);
            acc[2][1] = fmaf(av.z, bv.y, acc[2][1]);
            acc[2][2] = fmaf(av.z, bv.z, acc[2][2]);
            acc[2][3] = fmaf(av.z, bv.w, acc[2][3]);
            acc[3][0] = fmaf(av.w, bv.x, acc[3][0]);
            acc[3][1] = fmaf(av.w, bv.y, acc[3][1]);
            acc[3][2] = fmaf(av.w, bv.z, acc[3][2]);
            acc[3][3] = fmaf(av.w, bv.w, acc[3][3]);
        }
        __syncthreads();
    }
    // ---- epilogue 1: store outputs ----
    #pragma unroll
    for (int qi = 0; qi < 4; ++qi) {
        float4 o = make_float4(acc[qi][0], acc[qi][1], acc[qi][2], acc[qi][3]);
        *(float4*)(outp + (size_t)(q0 + qi0 + qi) * 64 + dj0) = o;
    }
    // ---- epilogue 2: fused BN stats (reuse Bt: P=sum, P2=sumsq; 16 q-groups) ----
    {
        float* P  = Bt;          // [16][64]
        float* P2 = Bt + 1024;   // [16][64]
        int g = t >> 4;          // q-group 0..15
        #pragma unroll
        for (int dd = 0; dd < 4; ++dd) {
            float sv = ((acc[0][dd] + acc[1][dd]) + acc[2][dd]) + acc[3][dd];
            float qv = fmaf(acc[3][dd], acc[3][dd],
                       fmaf(acc[2][dd], acc[2][dd],
                       fmaf(acc[1][dd], acc[1][dd], acc[0][dd] * acc[0][dd])));
            P [g * 64 + dj0 + dd] = sv;
            P2[g * 64 + dj0 + dd] = qv;
        }
        __syncthreads();
        if (t < 64) {
            float a = 0.f, b2 = 0.f;
            #pragma unroll
            for (int gg = 0; gg < 16; ++gg) {
                a  += P [gg * 64 + t];
                b2 += P2[gg * 64 + t];
            }
            atomicAdd(&sums[t], a);
            atomicAdd(&sums[64 + t], b2);
        }
    }
}

// ---------------- K3: BN + transpose (B,N,D) -> (B,D,N) ----------------
__global__ __launch_bounds__(256) void k_bn(const float* __restrict__ outp,
                                            const float* __restrict__ sums,
                                            const float* __restrict__ gamma,
                                            const float* __restrict__ beta,
                                            float* __restrict__ out) {
    __shared__ float tile[64][65];
    __shared__ float sa[64], sb[64];
    int lane = threadIdx.x & 63, wid = threadIdx.x >> 6;
    int b = blockIdx.x >> 7, nt = blockIdx.x & 127;
    int n0 = nt * 64;
    if (threadIdx.x < 64) {
        const float inv = 1.f / 32768.f;
        float mean = sums[threadIdx.x] * inv;
        float var = sums[64 + threadIdx.x] * inv - mean * mean;
        float rs = rsqrtf(var + 1e-5f);
        float a = rs * gamma[threadIdx.x];
        sa[threadIdx.x] = a;
        sb[threadIdx.x] = beta[threadIdx.x] - mean * a;
    }
    for (int rr = 0; rr < 16; ++rr) {
        int r = wid * 16 + rr;
        tile[r][lane] = outp[((size_t)(b * NPTS + n0 + r)) * 64 + lane];
    }
    __syncthreads();
    for (int rr = 0; rr < 16; ++rr) {
        int dr = wid * 16 + rr;
        out[((size_t)b * 64 + dr) * NPTS + n0 + lane] =
            fmaf(tile[lane][dr], sa[dr], sb[dr]);
    }
}

extern "C" void kernel_launch(void* const* d_in, const int* in_sizes, int n_in,
                              void* d_out, int out_size, void* d_ws, size_t ws_size,
                              hipStream_t stream) {
    (void)in_sizes; (void)n_in; (void)out_size; (void)ws_size;
    const float* x     = (const float*)d_in[0];  // (4,64,8192)
    const float* pos   = (const float*)d_in[1];  // (4,3,8192)
    const float* F     = (const float*)d_in[2];  // (16,64,64)
    const float* gamma = (const float*)d_in[3];  // (64,)
    const float* beta  = (const float*)d_in[4];  // (64,)
    float* out = (float*)d_out;                  // (4,64,8192)

    char* ws = (char*)d_ws;
    float* xT   = (float*)(ws + OFF_XT);
    float* Fb   = (float*)(ws + OFF_FBIG);
    float* sums = (float*)(ws + OFF_SUMS);
    int*   idx  = (int*)(ws + OFF_IDX);
    float* pre  = (float*)(ws + OFF_PRE);
    float* sqa  = (float*)(ws + OFF_SQ);   // aliases pre; consumed before conv

    k_prep<<<658, 256, 0, stream>>>(x, F, pos, xT, Fb, sums, sqa);
    k_knn<<<2048, 256, 0, stream>>>(pos, sqa, idx);
    k_conv<<<512, 256, 0, stream>>>(xT, Fb, idx, pre, sums);
    k_bn<<<512, 256, 0, stream>>>(pre, sums, gamma, beta, out);
}

// Round 21
// 282.771 us; speedup vs baseline: 1.1680x; 1.1680x over previous
//
#include <hip/hip_runtime.h>
#include <hip/hip_bf16.h>

// Problem constants (B=4, C=64, N=8192, K=16, D=64)
#define NPTS 8192
#define NQ   32768      // B*N
#define KNN  16
#define SCAP 112        // survivor cap per query (expected ~25-50)

// ws layout (bytes)
#define OFF_XT   0                      // B*N*C f32 = 8 MB  (x transposed to (B,N,C))
#define OFF_FBIG (8*1024*1024)          // 17*64*64 f32 = 278528 B (F with appended -sum(F))
#define OFF_SUMS (OFF_FBIG + 278528)    // 128 f32 (sum, sumsq per channel)
#define OFF_IDX  (OFF_SUMS + 512)       // B*N*16 int32 = 2 MB
#define OFF_PRE  (OFF_IDX + 2*1024*1024)// B*N*64 f32 = 8 MB (pre-BN output, (B*N, D))
// sq array (B*N f32 = 128 KB) ALIASES the start of PRE: k_prep writes it,
// k_knn consumes it, then k_conv overwrites PRE — stream-ordered, safe.
#define OFF_SQ   OFF_PRE

// Reference fp32 key — numpy execution model (verified R6, absmax 0.0156):
//   sq[m]   = (x*x + y*y) + z*z                  -- non-fused (np.sum(pos*pos))
//   inner   = fma(z,z', fma(y,y', rnd(x*x')))    -- einsum AVX2 axpy FMA chain
//   negd    = ((2*inner) - sq_n) - sq_m          -- elementwise, left-to-right
__device__ __forceinline__ float sq3(float x, float y, float z) {
    #pragma clang fp contract(off)
    float xx = x * x;
    float yy = y * y;
    float zz = z * z;
    return (xx + yy) + zz;
}
__device__ __forceinline__ float negd2(float qx, float qy, float qz, float sqn,
                                       float mx, float my, float mz, float sqm) {
    #pragma clang fp contract(off)
    float p0 = qx * mx;
    float inn = __builtin_fmaf(qz, mz, __builtin_fmaf(qy, my, p0));
    float t = 2.0f * inn;
    float u = t - sqn;
    return u - sqm;
}
// Filter margin: cheap fused key c~ = 2<q,m> - sqm differs from (exact key +
// sqn) by <= ~1e-4. 2e-3 is 20x conservative; two eps-steps cover tau-side
// and member-side error -> survivor set provably supersets the true top-16.
#define KEY_EPS2 2.0e-3f

// ---------------- K0: merged prep (transpose x | Fbig | zero sums | sq) ------
__global__ __launch_bounds__(256) void k_prep(const float* __restrict__ x,
                                              const float* __restrict__ F,
                                              const float* __restrict__ pos,
                                              float* __restrict__ xT,
                                              float* __restrict__ Fb,
                                              float* __restrict__ sums,
                                              float* __restrict__ sqa) {
    int bid = blockIdx.x;
    if (bid < 512) {
        __shared__ float tile[64][65];
        int lane = threadIdx.x & 63, wid = threadIdx.x >> 6;
        int b = bid >> 7, nt = bid & 127;
        int n0 = nt * 64;
        for (int rr = 0; rr < 16; ++rr) {
            int c = wid * 16 + rr;
            tile[c][lane] = x[((size_t)b * 64 + c) * NPTS + n0 + lane];
        }
        __syncthreads();
        for (int rr = 0; rr < 16; ++rr) {
            int r = wid * 16 + rr;
            xT[((size_t)(b * NPTS + n0 + r)) * 64 + lane] = tile[lane][r];
        }
    } else if (bid < 528) {
        int j = bid - 512;
        for (int e = threadIdx.x; e < 4096; e += 256)
            Fb[j * 4096 + e] = F[j * 4096 + e];
    } else if (bid == 528) {
        for (int e = threadIdx.x; e < 4096; e += 256) {
            float s = 0.f;
            for (int k = 0; k < 16; ++k) s += F[k * 4096 + e];
            Fb[16 * 4096 + e] = -s;
        }
    } else if (bid == 529) {
        if (threadIdx.x < 128) sums[threadIdx.x] = 0.f;
    } else {
        int g = (bid - 530) * 256 + threadIdx.x;   // 0..NQ-1
        int b = g >> 13, n = g & (NPTS - 1);
        const float* pb = pos + (size_t)b * 3 * NPTS;
        sqa[g] = sq3(pb[n], pb[NPTS + n], pb[2 * NPTS + n]);
    }
}

// ---------------- K1: kNN, 8 q/wave, L2 streaming (banked best, R13/R18) -----
// 139 µs local minimum across 7 structural variants: occupancy raise (R11),
// LDS candidate tiles (R12), launch-bounds (R13), pk math (R14), prefetch
// (R15), MFMA filter (R16/17), candidate-split (R19/20: spills, then LDS
// conflicts + pair-sync serialization). Occupancy is WORK-limited (4096 waves
// = 50% of slots at G=8); all attempts to manufacture more waves cost more
// than they recovered.
__global__ __launch_bounds__(256, 4) void k_knn(const float* __restrict__ pos,
                                                const float* __restrict__ sqa,
                                                int* __restrict__ idxo) {
    __shared__ int            cnt[32];
    __shared__ unsigned short sidx[32][SCAP];
    __shared__ float          skey[32][SCAP];
    __shared__ int            outI[32][16];
    int t = threadIdx.x, lane = t & 63, wid = t >> 6;
    int qblk = blockIdx.x * 32;               // 32 queries per block, same batch
    int b = qblk >> 13;
    const float* px = pos + (size_t)b * 3 * NPTS;
    const float* py = px + NPTS;
    const float* pz = py + NPTS;
    const float* sb = sqa + (size_t)b * NPTS;
    int n0 = (qblk & (NPTS - 1)) + wid * 8;   // this wave's first query

    float qxs[8], qys[8], qzs[8], sqs[8], tqx[8], tqy[8], tqz[8];
    #pragma unroll
    for (int i = 0; i < 8; ++i) {
        qxs[i] = px[n0 + i]; qys[i] = py[n0 + i]; qzs[i] = pz[n0 + i];
        sqs[i] = sb[n0 + i];
        tqx[i] = 2.0f * qxs[i]; tqy[i] = 2.0f * qys[i]; tqz[i] = 2.0f * qzs[i];
    }
    if (lane < 8) cnt[wid * 8 + lane] = 0;    // wave-private lists
    if (lane < 16) {
        #pragma unroll
        for (int i = 0; i < 8; ++i) outI[wid * 8 + i][lane] = n0 + i;  // fallback
    }

    // pass 1: per-lane max of cheap key (3 FMA/cand; max3-friendly tree)
    float lm[8];
    #pragma unroll
    for (int i = 0; i < 8; ++i) lm[i] = -3.4e38f;
    for (int it = 0; it < 32; ++it) {
        int m = it * 256 + lane * 4;
        float4 X = *(const float4*)(px + m);
        float4 Y = *(const float4*)(py + m);
        float4 Z = *(const float4*)(pz + m);
        float4 S = *(const float4*)(sb + m);
        #pragma unroll
        for (int i = 0; i < 8; ++i) {
            float a0 = __builtin_fmaf(tqx[i], X.x, __builtin_fmaf(tqy[i], Y.x, __builtin_fmaf(tqz[i], Z.x, -S.x)));
            float a1 = __builtin_fmaf(tqx[i], X.y, __builtin_fmaf(tqy[i], Y.y, __builtin_fmaf(tqz[i], Z.y, -S.y)));
            float a2 = __builtin_fmaf(tqx[i], X.z, __builtin_fmaf(tqy[i], Y.z, __builtin_fmaf(tqz[i], Z.z, -S.z)));
            float a3 = __builtin_fmaf(tqx[i], X.w, __builtin_fmaf(tqy[i], Y.w, __builtin_fmaf(tqz[i], Z.w, -S.w)));
            // v_max3 x2: max3(a0,a1,a2), then max3(that,a3,lm)
            float m012 = fmaxf(fmaxf(a0, a1), a2);
            lm[i] = fmaxf(fmaxf(m012, a3), lm[i]);
        }
    }

    // thr[i] = (16th largest of 64 lane maxima) - 2*eps
    float thr[8];
    #pragma unroll
    for (int i = 0; i < 8; ++i) {
        float val = lm[i], tv = 0.f;
        for (int r = 0; r < 16; ++r) {
            float mm = val;
            mm = fmaxf(mm, __shfl_xor(mm, 1, 64));
            mm = fmaxf(mm, __shfl_xor(mm, 2, 64));
            mm = fmaxf(mm, __shfl_xor(mm, 4, 64));
            mm = fmaxf(mm, __shfl_xor(mm, 8, 64));
            mm = fmaxf(mm, __shfl_xor(mm, 16, 64));
            mm = fmaxf(mm, __shfl_xor(mm, 32, 64));
            tv = mm;
            if (val == mm) val = -3.4e38f;   // ties pop together: tau shrinks -> superset
        }
        thr[i] = tv - KEY_EPS2;
    }

    // pass 2: collect survivor indices (hits rare -> execz-skipped bodies)
    for (int it = 0; it < 32; ++it) {
        int m = it * 256 + lane * 4;
        float4 X = *(const float4*)(px + m);
        float4 Y = *(const float4*)(py + m);
        float4 Z = *(const float4*)(pz + m);
        float4 S = *(const float4*)(sb + m);
        #pragma unroll
        for (int i = 0; i < 8; ++i) {
            int lq = wid * 8 + i;
            float a0 = __builtin_fmaf(tqx[i], X.x, __builtin_fmaf(tqy[i], Y.x, __builtin_fmaf(tqz[i], Z.x, -S.x)));
            float a1 = __builtin_fmaf(tqx[i], X.y, __builtin_fmaf(tqy[i], Y.y, __builtin_fmaf(tqz[i], Z.y, -S.y)));
            float a2 = __builtin_fmaf(tqx[i], X.z, __builtin_fmaf(tqy[i], Y.z, __builtin_fmaf(tqz[i], Z.z, -S.z)));
            float a3 = __builtin_fmaf(tqx[i], X.w, __builtin_fmaf(tqy[i], Y.w, __builtin_fmaf(tqz[i], Z.w, -S.w)));
            if (a0 >= thr[i]) { int s_ = atomicAdd(&cnt[lq],1); if (s_<SCAP) sidx[lq][s_] = (unsigned short)m; }
            if (a1 >= thr[i]) { int s_ = atomicAdd(&cnt[lq],1); if (s_<SCAP) sidx[lq][s_] = (unsigned short)(m+1); }
            if (a2 >= thr[i]) { int s_ = atomicAdd(&cnt[lq],1); if (s_<SCAP) sidx[lq][s_] = (unsigned short)(m+2); }
            if (a3 >= thr[i]) { int s_ = atomicAdd(&cnt[lq],1); if (s_<SCAP) sidx[lq][s_] = (unsigned short)(m+3); }
        }
    }

    // phase A: exact reference key per survivor (scattered L2 loads, rare)
    #pragma unroll 1
    for (int i = 0; i < 8; ++i) {
        int lq = wid * 8 + i;
        int S = cnt[lq]; if (S > SCAP) S = SCAP;
        for (int p = lane; p < S; p += 64) {
            int m = sidx[lq][p];
            skey[lq][p] = negd2(qxs[i], qys[i], qzs[i], sqs[i],
                                px[m], py[m], pz[m], sb[m]);
        }
    }

    // phase B: exact rerank; ties -> lower index (lax.top_k semantics)
    #pragma unroll 1
    for (int i = 0; i < 8; ++i) {
        int lq = wid * 8 + i;
        int S = cnt[lq]; if (S > SCAP) S = SCAP;
        for (int p = lane; p < S; p += 64) {
            int m = sidx[lq][p];
            float km = skey[lq][p];
            int rank = 0;
            for (int j = 0; j < S; ++j) {
                float kj = skey[lq][j];
                int ij = sidx[lq][j];
                if (kj > km || (kj == km && ij < m)) rank++;
            }
            if (rank < KNN) outI[lq][rank] = m;
        }
    }
    __syncthreads();
    // write out 32 queries x 16 ranks
    #pragma unroll
    for (int h = 0; h < 2; ++h) {
        int lq = h * 16 + (t >> 4);
        idxo[(size_t)(qblk + lq) * KNN + (t & 15)] = outI[lq][t & 15];
    }
}

// ---------------- K2: gather + GEMM + fused BN-stats (R13 proven) ------------
// 64q x 64d tile, 256 threads, 4x4 micro, 2 blocks/CU. LDS-pipe-bound
// (17408 ds_read_b128/CU x ~12cyc = 87 µs — matches measured). R10/R14
// bigger-micro variants both cliffed on occupancy; keep this shape.
#define CPAD 68
__global__ __launch_bounds__(256) void k_conv(const float* __restrict__ xT,
                                              const float* __restrict__ Fb,
                                              const int* __restrict__ idx,
                                              float* __restrict__ outp,
                                              float* __restrict__ sums) {
    __shared__ float At[64][CPAD];
    __shared__ float Bt[64 * 64];
    int t = threadIdx.x;
    int q0 = blockIdx.x * 64;                 // tile base (same batch: 8192%64==0)
    int bbase = q0 & ~(NPTS - 1);             // batch row offset in xT
    int qi0 = (t >> 4) * 4;                   // query sub-block 0..60
    int dj0 = (t & 15) * 4;                   // d sub-block 0..60
    int r = t & 63;                           // gather row
    int s = t >> 6;                           // 16-float segment

    float acc[4][4];
    #pragma unroll
    for (int a = 0; a < 4; ++a)
        #pragma unroll
        for (int bb = 0; bb < 4; ++bb) acc[a][bb] = 0.f;

    for (int j = 0; j < 17; ++j) {
        // ---- stage A: gather 64 neighbor rows, store transposed ----
        {
            int qg = q0 + r;
            int nbr = (j < 16) ? (idx[(size_t)qg * KNN + j] & (NPTS - 1))
                               : (qg & (NPTS - 1));
            const float* src = xT + ((size_t)(bbase + nbr) * 64 + s * 16);
            float4 v0 = *(const float4*)(src);
            float4 v1 = *(const float4*)(src + 4);
            float4 v2 = *(const float4*)(src + 8);
            float4 v3 = *(const float4*)(src + 12);
            int c0 = s * 16;
            At[c0+ 0][r] = v0.x; At[c0+ 1][r] = v0.y; At[c0+ 2][r] = v0.z; At[c0+ 3][r] = v0.w;
            At[c0+ 4][r] = v1.x; At[c0+ 5][r] = v1.y; At[c0+ 6][r] = v1.z; At[c0+ 7][r] = v1.w;
            At[c0+ 8][r] = v2.x; At[c0+ 9][r] = v2.y; At[c0+10][r] = v2.z; At[c0+11][r] = v2.w;
            At[c0+12][r] = v3.x; At[c0+13][r] = v3.y; At[c0+14][r] = v3.z; At[c0+15][r] = v3.w;
        }
        // ---- stage B: copy F[j] (4096 floats) ----
        {
            const float* fj = Fb + j * 4096;
            #pragma unroll
            for (int u = 0; u < 4; ++u) {
                int e = u * 1024 + t * 4;
                *(float4*)&Bt[e] = *(const float4*)(fj + e);
            }
        }
        __syncthreads();
        // ---- compute: 64 k-steps ----
        #pragma unroll 8
        for (int k = 0; k < 64; ++k) {
            float4 av = *(const float4*)&At[k][qi0];
            float4 bv = *(const float4*)&Bt[k * 64 + dj0];
            acc[0][0] = fmaf(av.x, bv.x, acc[0][0]);
            acc[0][1] = fmaf(av.x, bv.y, acc[0][1]);
            acc[0][2] = fmaf(av.x, bv.z, acc[0][2]);
            acc[0][3] = fmaf(av.x, bv.w, acc[0][3]);
            acc[1][0] = fmaf(av.y, bv.x, acc[1][0]);
            acc[1][1] = fmaf(av.y, bv.y, acc[1][1]);
            acc[1][2] = fmaf(av.y, bv.z, acc[1][2]);
            acc[1][3] = fmaf(av.y, bv.w, acc[1][3]);
            acc[2][0] = fmaf(av.z, bv.x, acc[2][0]);
            acc[2][1] = fmaf(av.z, bv.y, acc[2][1]);
            acc[2][2] = fmaf(av.z, bv.z, acc[2][2]);
            acc[2][3] = fmaf(av.z, bv.w, acc[2][3]);
            acc[3][0] = fmaf(av.w, bv.x, acc[3][0]);
            acc[3][1] = fmaf(av.w, bv.y, acc[3][1]);
            acc[3][2] = fmaf(av.w, bv.z, acc[3][2]);
            acc[3][3] = fmaf(av.w, bv.w, acc[3][3]);
        }
        __syncthreads();
    }
    // ---- epilogue 1: store outputs ----
    #pragma unroll
    for (int qi = 0; qi < 4; ++qi) {
        float4 o = make_float4(acc[qi][0], acc[qi][1], acc[qi][2], acc[qi][3]);
        *(float4*)(outp + (size_t)(q0 + qi0 + qi) * 64 + dj0) = o;
    }
    // ---- epilogue 2: fused BN stats (reuse Bt: P=sum, P2=sumsq; 16 q-groups) ----
    {
        float* P  = Bt;          // [16][64]
        float* P2 = Bt + 1024;   // [16][64]
        int g = t >> 4;          // q-group 0..15
        #pragma unroll
        for (int dd = 0; dd < 4; ++dd) {
            float sv = ((acc[0][dd] + acc[1][dd]) + acc[2][dd]) + acc[3][dd];
            float qv = fmaf(acc[3][dd], acc[3][dd],
                       fmaf(acc[2][dd], acc[2][dd],
                       fmaf(acc[1][dd], acc[1][dd], acc[0][dd] * acc[0][dd])));
            P [g * 64 + dj0 + dd] = sv;
            P2[g * 64 + dj0 + dd] = qv;
        }
        __syncthreads();
        if (t < 64) {
            float a = 0.f, b2 = 0.f;
            #pragma unroll
            for (int gg = 0; gg < 16; ++gg) {
                a  += P [gg * 64 + t];
                b2 += P2[gg * 64 + t];
            }
            atomicAdd(&sums[t], a);
            atomicAdd(&sums[64 + t], b2);
        }
    }
}

// ---------------- K3: BN + transpose (B,N,D) -> (B,D,N) ----------------
__global__ __launch_bounds__(256) void k_bn(const float* __restrict__ outp,
                                            const float* __restrict__ sums,
                                            const float* __restrict__ gamma,
                                            const float* __restrict__ beta,
                                            float* __restrict__ out) {
    __shared__ float tile[64][65];
    __shared__ float sa[64], sb[64];
    int lane = threadIdx.x & 63, wid = threadIdx.x >> 6;
    int b = blockIdx.x >> 7, nt = blockIdx.x & 127;
    int n0 = nt * 64;
    if (threadIdx.x < 64) {
        const float inv = 1.f / 32768.f;
        float mean = sums[threadIdx.x] * inv;
        float var = sums[64 + threadIdx.x] * inv - mean * mean;
        float rs = rsqrtf(var + 1e-5f);
        float a = rs * gamma[threadIdx.x];
        sa[threadIdx.x] = a;
        sb[threadIdx.x] = beta[threadIdx.x] - mean * a;
    }
    for (int rr = 0; rr < 16; ++rr) {
        int r = wid * 16 + rr;
        tile[r][lane] = outp[((size_t)(b * NPTS + n0 + r)) * 64 + lane];
    }
    __syncthreads();
    for (int rr = 0; rr < 16; ++rr) {
        int dr = wid * 16 + rr;
        out[((size_t)b * 64 + dr) * NPTS + n0 + lane] =
            fmaf(tile[lane][dr], sa[dr], sb[dr]);
    }
}

extern "C" void kernel_launch(void* const* d_in, const int* in_sizes, int n_in,
                              void* d_out, int out_size, void* d_ws, size_t ws_size,
                              hipStream_t stream) {
    (void)in_sizes; (void)n_in; (void)out_size; (void)ws_size;
    const float* x     = (const float*)d_in[0];  // (4,64,8192)
    const float* pos   = (const float*)d_in[1];  // (4,3,8192)
    const float* F     = (const float*)d_in[2];  // (16,64,64)
    const float* gamma = (const float*)d_in[3];  // (64,)
    const float* beta  = (const float*)d_in[4];  // (64,)
    float* out = (float*)d_out;                  // (4,64,8192)

    char* ws = (char*)d_ws;
    float* xT   = (float*)(ws + OFF_XT);
    float* Fb   = (float*)(ws + OFF_FBIG);
    float* sums = (float*)(ws + OFF_SUMS);
    int*   idx  = (int*)(ws + OFF_IDX);
    float* pre  = (float*)(ws + OFF_PRE);
    float* sqa  = (float*)(ws + OFF_SQ);   // aliases pre; consumed before conv

    k_prep<<<658, 256, 0, stream>>>(x, F, pos, xT, Fb, sums, sqa);
    k_knn<<<1024, 256, 0, stream>>>(pos, sqa, idx);
    k_conv<<<512, 256, 0, stream>>>(xT, Fb, idx, pre, sums);
    k_bn<<<512, 256, 0, stream>>>(pre, sums, gamma, beta, out);
}